// Round 6
// baseline (428.033 us; speedup 1.0000x reference)
//
#include <hip/hip_runtime.h>
#include <hip/hip_bf16.h>
#include <cstdint>

typedef __attribute__((ext_vector_type(4))) float f32x4;
typedef __attribute__((ext_vector_type(4))) int i32x4;

#define IN_F 4096
#define OUT_F 4096
#define N_TOK 8192
#define NUM_FREQ 16
#define RROWS 4  // W rows per block (amortizes per-column cosines 4x)

// ---------- helpers ----------

__device__ inline float fast_tanh(float x) {
    float ax = fabsf(x);
    float e = __expf(2.0f * ax);
    float t = 1.0f - 2.0f / (e + 1.0f);
    return copysignf(t, x);
}

__device__ inline void load_lds16(const void* g, void* l) {
    __builtin_amdgcn_global_load_lds(
        (const __attribute__((address_space(1))) void*)(uintptr_t)g,
        (__attribute__((address_space(3))) void*)(uint32_t)(uintptr_t)l,
        16, 0, 0);
}

__device__ inline int q8(float v, float s) {
    int q = (int)rintf(v * s);
    return min(127, max(-127, q));
}

__device__ inline unsigned int pack4(int q0, int q1, int q2, int q3) {
    return (q0 & 255) | ((q1 & 255) << 8) | ((q2 & 255) << 16) |
           ((q3 & 255) << 24);
}

// ---------- kernel 1: fused W synthesis->i8 + x quantize->i8 ----------
// (unchanged from round 3 — verified passing)
__global__ __launch_bounds__(256)
void prep(const float* __restrict__ x, signed char* __restrict__ xq,
          float* __restrict__ sx, const float* __restrict__ amp,
          const float* __restrict__ rf, const float* __restrict__ cf,
          const float* __restrict__ rp, const float* __restrict__ cp,
          const float* __restrict__ lA, const float* __restrict__ lB,
          const float* __restrict__ alpha, const float* __restrict__ beta,
          signed char* __restrict__ wq, float* __restrict__ sw) {
    const int tid = threadIdx.x;
    const int wave = tid >> 6;
    const int lane = tid & 63;
    __shared__ float s_s[RROWS][NUM_FREQ];
    __shared__ float red[RROWS][4];

    if (blockIdx.x < OUT_F / RROWS) {
        const int o0 = blockIdx.x * RROWS;
        const float step = 6.28318530717958647692f / 4095.0f;
        if (tid < RROWS * NUM_FREQ) {
            const int r = tid >> 4;
            const int k = tid & 15;
            s_s[r][k] =
                amp[k] * __sinf(step * (float)(o0 + r) * rf[k] + rp[k]);
        }
        __syncthreads();

        const int g = lane >> 2;   // element sub-index within 16-group
        const int q = lane & 3;    // freq quad owned by this lane

        float cfr[4], cpr[4];
#pragma unroll
        for (int e = 0; e < 4; ++e) {
            cfr[e] = cf[q * 4 + e];
            cpr[e] = cp[q * 4 + e];
        }
        float skr[RROWS][4];
#pragma unroll
        for (int r = 0; r < RROWS; ++r)
#pragma unroll
            for (int e = 0; e < 4; ++e) skr[r][e] = s_s[r][q * 4 + e];

        const float sa = 1.0f / (1.0f + __expf(-alpha[0]));
        const float sb = 1.0f / (1.0f + __expf(-beta[0]));
        const float stdv = 0.015625f;  // sqrt(2/8192) = 1/64 exactly
        float a0r[RROWS], a1r[RROWS];
#pragma unroll
        for (int r = 0; r < RROWS; ++r) {
            a0r[r] = lA[(o0 + r) * 2 + 0];
            a1r[r] = lA[(o0 + r) * 2 + 1];
        }

        const int ibw = wave * 1024;
        float w[RROWS][16];

#pragma unroll
        for (int j = 0; j < 16; ++j) {
#pragma unroll
            for (int sq = 0; sq < 4; ++sq) {
                const int i = ibw + (j * 4 + sq) * 16 + g;
                const float ci = step * (float)i;
                float cv[4];
#pragma unroll
                for (int e = 0; e < 4; ++e)
                    cv[e] = __cosf(ci * cfr[e] + cpr[e]);
#pragma unroll
                for (int r = 0; r < RROWS; ++r) {
                    float p = skr[r][0] * cv[0] + skr[r][1] * cv[1] +
                              skr[r][2] * cv[2] + skr[r][3] * cv[3];
                    p += __shfl_xor(p, 1);
                    p += __shfl_xor(p, 2);
                    if (q == sq) w[r][j] = p;
                }
            }
        }

#pragma unroll
        for (int j = 0; j < 16; ++j) {
            const int i = ibw + (j * 4 + q) * 16 + g;
            const float b0 = lB[i];
            const float b1 = lB[IN_F + i];
#pragma unroll
            for (int r = 0; r < RROWS; ++r) {
                const float wl = a0r[r] * b0 + a1r[r] * b1;
                w[r][j] = sa * stdv * fast_tanh(w[r][j]) +
                          sb * stdv * fast_tanh(wl);
            }
        }

        float m[RROWS];
#pragma unroll
        for (int r = 0; r < RROWS; ++r) {
            float mm = 0.0f;
#pragma unroll
            for (int j = 0; j < 16; ++j) mm = fmaxf(mm, fabsf(w[r][j]));
#pragma unroll
            for (int off = 32; off > 0; off >>= 1)
                mm = fmaxf(mm, __shfl_xor(mm, off));
            m[r] = mm;
        }
        if (lane == 0) {
#pragma unroll
            for (int r = 0; r < RROWS; ++r) red[r][wave] = m[r];
        }
        __syncthreads();
#pragma unroll
        for (int r = 0; r < RROWS; ++r) {
            float mm = fmaxf(fmaxf(red[r][0], red[r][1]),
                             fmaxf(red[r][2], red[r][3]));
            m[r] = fmaxf(mm, 1e-20f);
        }

#pragma unroll
        for (int r = 0; r < RROWS; ++r) {
            const float s = 127.0f / m[r];
            signed char* wrow = wq + (size_t)(o0 + r) * IN_F;
#pragma unroll
            for (int j = 0; j < 16; ++j) {
                const int i = ibw + (j * 4 + q) * 16 + g;
                wrow[i] = (signed char)q8(w[r][j], s);
            }
        }
        if (tid == 0) {
#pragma unroll
            for (int r = 0; r < RROWS; ++r) sw[o0 + r] = m[r] / 127.0f;
        }
    } else {
        const int t = blockIdx.x - OUT_F / RROWS;
        const f32x4* xr = (const f32x4*)(x + (size_t)t * IN_F);
        f32x4 v[4];
#pragma unroll
        for (int j = 0; j < 4; ++j) v[j] = xr[tid + 256 * j];
        float m = 0.0f;
#pragma unroll
        for (int j = 0; j < 4; ++j)
#pragma unroll
            for (int e = 0; e < 4; ++e) m = fmaxf(m, fabsf(v[j][e]));
#pragma unroll
        for (int off = 32; off > 0; off >>= 1)
            m = fmaxf(m, __shfl_xor(m, off));
        if (lane == 0) red[0][wave] = m;
        __syncthreads();
        m = fmaxf(fmaxf(red[0][0], red[0][1]), fmaxf(red[0][2], red[0][3]));
        m = fmaxf(m, 1e-20f);
        const float s = 127.0f / m;
        unsigned int* orow = (unsigned int*)(xq + (size_t)t * IN_F);
#pragma unroll
        for (int j = 0; j < 4; ++j)
            orow[tid + 256 * j] =
                pack4(q8(v[j][0], s), q8(v[j][1], s), q8(v[j][2], s),
                      q8(v[j][3], s));
        if (tid == 0) sx[t] = m / 127.0f;
    }
}

// ---------- kernel 2: i8 MFMA GEMM, true 8-phase interleave ----------
// Round-6 fix of round-5's neutral result. R5 had {bar; reads; lgk(0);
// bar; MFMA} -> reads and MFMA in lockstep ALTERNATION (LDS 1152cyc +
// MFMA 1305cyc serialized per half-phase = the measured 163us). Template
// phase is {reads; stage; bar; lgk(0); MFMA; bar}: read latency hides
// under the barrier wait, and the next phase's read burst overlaps the
// previous phase's in-flight MFMA pipe work (s_barrier doesn't drain the
// matrix pipe). Register rotation makes adjacent phases WAR-free:
//   slice t (even): phA writes afl+bva, MFMAs afl x bva -> acc[0:4]
//                   phB writes afh,     MFMAs afh x bva -> acc[4:8]
//   slice t+1 (odd): same with bvb. Adjacent-phase written-set vs
//   in-flight-MFMA-read-set intersection = empty for all 4 pairs.
// K-slice = 64B; ring of 4 slots (A 16K + B 16K each = 128 KiB LDS);
// slot for slice u staged during slice u-3 (H0 in phA, H1 in phB).
// vmcnt once per slice: steady 8 (= slots t+2,t+3 in flight), tails
// 4 (t==NT-3) then 0. Gate for slot t+1's reads = that vmcnt + the two
// following barriers. Swizzle & numerics identical (verified, 0 confl).
#define BM 256
#define BN 256
#define SUBK 64

__global__ __launch_bounds__(512, 2)
void gemm_i8(const signed char* __restrict__ A, const signed char* __restrict__ B,
             const float* __restrict__ sx, const float* __restrict__ sw,
             const float* __restrict__ bias, float* __restrict__ C,
             int M, int N, int K) {
    // slot s in [0,4): A at lds[s<<14], B at lds[65536 + (s<<14)]
    __shared__ signed char lds[131072];

    const int tid = threadIdx.x;
    const int wave = tid >> 6;
    const int lane = tid & 63;

    const int bm = blockIdx.y * BM;
    const int bn = blockIdx.x * BN;

    // staging: one call = 16 rows x 64B (1KB, linear in LDS dest).
    // lane l -> row l>>2, source 16B-unit = (l&3) ^ ((l>>3)&3)  [swizzle]
    const int srow = lane >> 2;
    const int scol = (((lane & 3) ^ ((lane >> 3) & 3)) << 4);

    const signed char* gA = A + (size_t)(bm + wave * 16 + srow) * K + scol;
    const signed char* gB = B + (size_t)(bn + wave * 16 + srow) * K + scol;
    const size_t rowK = (size_t)128 * K;  // second 128-row chunk

    // reads: row = wtile + i*16 + lm; 16B unit = quad ^ ((lm>>1)&3)
    const int lm = lane & 15;
    const int quad = lane >> 4;
    const int kq = ((quad ^ ((lm >> 1) & 3)) << 4);

    const int wm = (wave & 1) * 128;   // wave M offset in tile
    const int wn = (wave >> 1) * 64;   // wave N offset in tile
    const int aoff = (wm + lm) * SUBK + kq;
    const int boff = (wn + lm) * SUBK + kq;

    const int NT = K >> 6;  // 64B k-slices

    // half-stages: H0 = first 128 rows of A and B panels, H1 = second 128
    auto STAGE_H0 = [&](int slot, int tt) {
        load_lds16(gA + (size_t)tt * SUBK, &lds[(slot << 14) + wave * 1024]);
        load_lds16(gB + (size_t)tt * SUBK,
                   &lds[65536 + (slot << 14) + wave * 1024]);
    };
    auto STAGE_H1 = [&](int slot, int tt) {
        load_lds16(gA + rowK + (size_t)tt * SUBK,
                   &lds[(slot << 14) + wave * 1024 + 8192]);
        load_lds16(gB + rowK + (size_t)tt * SUBK,
                   &lds[65536 + (slot << 14) + wave * 1024 + 8192]);
    };

    i32x4 acc[8][4] = {};
    i32x4 afl[4], afh[4], bva[4], bvb[4];

// one k-slice = 2 phases. BVN = bva (even t) / bvb (odd t): static reg
// choice via 2x-unrolled loop (rule #20: no runtime-indexed reg arrays).
#define SLICE(T, BVN)                                                       \
    {                                                                       \
        const int slot_ = (T) & 3;                                          \
        const signed char* pa_ = &lds[slot_ << 14];                         \
        const signed char* pb_ = &lds[65536 + (slot_ << 14)];               \
        _Pragma("unroll") for (int i = 0; i < 4; ++i)                       \
            afl[i] = *(const i32x4*)(pa_ + aoff + i * 1024);                \
        _Pragma("unroll") for (int i = 0; i < 4; ++i)                       \
            BVN[i] = *(const i32x4*)(pb_ + boff + i * 1024);                \
        if ((T) + 3 < NT) STAGE_H0(((T) + 3) & 3, (T) + 3);                 \
        __builtin_amdgcn_s_barrier();                                       \
        asm volatile("s_waitcnt lgkmcnt(0)" ::: "memory");                  \
        __builtin_amdgcn_sched_barrier(0);                                  \
        __builtin_amdgcn_s_setprio(1);                                      \
        _Pragma("unroll") for (int im = 0; im < 4; ++im)                    \
            _Pragma("unroll") for (int in = 0; in < 4; ++in)                \
                acc[im][in] = __builtin_amdgcn_mfma_i32_16x16x64_i8(        \
                    afl[im], BVN[in], acc[im][in], 0, 0, 0);                \
        __builtin_amdgcn_s_setprio(0);                                      \
        __builtin_amdgcn_s_barrier();                                       \
        _Pragma("unroll") for (int i = 0; i < 4; ++i)                       \
            afh[i] = *(const i32x4*)(pa_ + aoff + 4096 + i * 1024);         \
        if ((T) + 3 < NT) STAGE_H1(((T) + 3) & 3, (T) + 3);                 \
        if ((T) < NT - 3)                                                   \
            asm volatile("s_waitcnt vmcnt(8)" ::: "memory");                \
        else if ((T) == NT - 3)                                             \
            asm volatile("s_waitcnt vmcnt(4)" ::: "memory");                \
        else                                                                \
            asm volatile("s_waitcnt vmcnt(0)" ::: "memory");                \
        __builtin_amdgcn_s_barrier();                                       \
        asm volatile("s_waitcnt lgkmcnt(0)" ::: "memory");                  \
        __builtin_amdgcn_sched_barrier(0);                                  \
        __builtin_amdgcn_s_setprio(1);                                      \
        _Pragma("unroll") for (int im = 0; im < 4; ++im)                    \
            _Pragma("unroll") for (int in = 0; in < 4; ++in)                \
                acc[im + 4][in] = __builtin_amdgcn_mfma_i32_16x16x64_i8(    \
                    afh[im], BVN[in], acc[im + 4][in], 0, 0, 0);            \
        __builtin_amdgcn_s_setprio(0);                                      \
        __builtin_amdgcn_s_barrier();                                       \
    }

    // prologue: stage slots for slices 0,1,2; gate slice-0 reads
    STAGE_H0(0, 0); STAGE_H1(0, 0);
    STAGE_H0(1, 1); STAGE_H1(1, 1);
    STAGE_H0(2, 2); STAGE_H1(2, 2);
    asm volatile("s_waitcnt vmcnt(8)" ::: "memory");
    __builtin_amdgcn_s_barrier();

    for (int t = 0; t < NT; t += 2) {
        SLICE(t, bva);
        SLICE(t + 1, bvb);
    }
#undef SLICE

    // epilogue: D layout col = lane&15, row = quad*4 + r
    float sxv[8][4];
#pragma unroll
    for (int im = 0; im < 8; ++im)
#pragma unroll
        for (int r = 0; r < 4; ++r)
            sxv[im][r] = sx[bm + wm + im * 16 + quad * 4 + r];

#pragma unroll
    for (int in = 0; in < 4; ++in) {
        const int cn = bn + wn + in * 16 + lm;
        const float bv_ = bias[cn];
        const float scw = sw[cn];
#pragma unroll
        for (int im = 0; im < 8; ++im) {
            const int rm = bm + wm + im * 16 + quad * 4;
#pragma unroll
            for (int r = 0; r < 4; ++r)
                C[(size_t)(rm + r) * N + cn] =
                    (float)acc[im][in][r] * (sxv[im][r] * scw) + bv_;
        }
    }
}

// ---------- launch ----------
extern "C" void kernel_launch(void* const* d_in, const int* in_sizes, int n_in,
                              void* d_out, int out_size, void* d_ws,
                              size_t ws_size, hipStream_t stream) {
    const float* x = (const float*)d_in[0];
    const float* amp = (const float*)d_in[1];
    const float* rf = (const float*)d_in[2];
    const float* cf = (const float*)d_in[3];
    const float* rp = (const float*)d_in[4];
    const float* cp = (const float*)d_in[5];
    const float* lA = (const float*)d_in[6];
    const float* lB = (const float*)d_in[7];
    const float* alpha = (const float*)d_in[8];
    const float* beta = (const float*)d_in[9];
    const float* bias = (const float*)d_in[10];
    float* out = (float*)d_out;

    signed char* wq = (signed char*)d_ws;                       // 16 MiB
    signed char* xq = wq + (size_t)OUT_F * IN_F;                // 32 MiB
    float* sw = (float*)(xq + (size_t)N_TOK * IN_F);            // 16 KiB
    float* sx = sw + OUT_F;                                     // 32 KiB

    prep<<<OUT_F / RROWS + N_TOK, 256, 0, stream>>>(
        x, xq, sx, amp, rf, cf, rp, cp, lA, lB, alpha, beta, wq, sw);
    gemm_i8<<<dim3(OUT_F / BN, N_TOK / BM), 512, 0, stream>>>(
        xq, wq, sx, sw, bias, out, N_TOK, OUT_F, IN_F);
}